// Round 1
// 1677.807 us; speedup vs baseline: 1.0560x; 1.0560x over previous
//
#include <hip/hip_runtime.h>
#include <hip/hip_bf16.h>
#include <stdint.h>

#define N_ENT 100000
#define N_REL 500
#define DIM   1024
#define BATCH 1024
#define K2    2048          // concat(re, im) along K

#define BM 128
#define BN 128
#define BK 32
#define MTILES 8            // 1024 / 128
#define NTILES 782          // ceil(100000 / 128)
#define GRID   (MTILES * NTILES)   // 6256, divisible by 8 (XCD swizzle valid)
#define NPAD   (NTILES * BN)       // 100096 — padded entity rows in bf16 E

typedef __attribute__((ext_vector_type(8))) short bf16x8;
typedef __attribute__((ext_vector_type(4))) float f32x4;
typedef __attribute__((ext_vector_type(4))) unsigned int u32x4;

__device__ __forceinline__ unsigned short f2bf_rne(float x) {
    unsigned int u = __float_as_uint(x);
    u += 0x7fffu + ((u >> 16) & 1u);
    return (unsigned short)(u >> 16);
}

// pack bf16(a) into low half, bf16(b) into high half (truncation — error
// budget analysis: bias ~0.2% per operand, absmax impact ~1 vs threshold 29)
__device__ __forceinline__ unsigned int pack2_bf16_trunc(float a, float b) {
    return __builtin_amdgcn_perm(__float_as_uint(b), __float_as_uint(a), 0x07060302u);
}

// async global->LDS, 16 bytes per lane; LDS dest must be wave-uniform-base + lane*16
__device__ __forceinline__ void gld_lds16(const void* g, void* l) {
    __builtin_amdgcn_global_load_lds(
        (const __attribute__((address_space(1))) void*)(uintptr_t)g,
        (__attribute__((address_space(3))) void*)(unsigned int)(uintptr_t)l,
        16, 0, 0);
}

// Kernel 1: A[b][0:1024] = h_re*cos - h_im*sin ; A[b][1024:2048] = h_re*sin + h_im*cos  (bf16)
__global__ __launch_bounds__(256) void rotate_build_A(
    const int* __restrict__ e1, const int* __restrict__ rr,
    const float* __restrict__ ent_re, const float* __restrict__ ent_im,
    const float* __restrict__ rel_phase, unsigned short* __restrict__ A)
{
    const int b = blockIdx.x;
    const int t = threadIdx.x;           // 256 threads * 4 elems = 1024 = DIM
    const long h   = e1[b];
    const long rel = rr[b];
    float4 hr = ((const float4*)(ent_re + h * DIM))[t];
    float4 hi = ((const float4*)(ent_im + h * DIM))[t];
    float4 ph = ((const float4*)(rel_phase + rel * DIM))[t];
    float hrf[4] = {hr.x, hr.y, hr.z, hr.w};
    float hif[4] = {hi.x, hi.y, hi.z, hi.w};
    float phf[4] = {ph.x, ph.y, ph.z, ph.w};
    unsigned short re[4], im[4];
    #pragma unroll
    for (int i = 0; i < 4; ++i) {
        float s, c;
        __sincosf(phf[i], &s, &c);
        re[i] = f2bf_rne(hrf[i] * c - hif[i] * s);
        im[i] = f2bf_rne(hrf[i] * s + hif[i] * c);
    }
    ((ushort4*)(A + (size_t)b * K2))[t]       = make_ushort4(re[0], re[1], re[2], re[3]);
    ((ushort4*)(A + (size_t)b * K2 + DIM))[t] = make_ushort4(im[0], im[1], im[2], im[3]);
}

// Kernel 1b: pre-convert E to bf16 once: Eb[n][0:1024]=bf16(ent_re[n]),
// Eb[n][1024:2048]=bf16(ent_im[n]); rows n >= N_ENT zero-padded.
// Pure BW pass: 819 MB read + 410 MB write. Grid-stride, 2048 blocks.
__global__ __launch_bounds__(256) void convert_E(
    const float* __restrict__ ent_re, const float* __restrict__ ent_im,
    unsigned short* __restrict__ Eb)
{
    const int total = NPAD * 256;        // one unit = 8 bf16 elements (16B store)
    for (int u = blockIdx.x * 256 + threadIdx.x; u < total; u += gridDim.x * 256) {
        const int n  = u >> 8;
        const int k0 = (u & 255) * 8;
        u32x4 w;
        if (n < N_ENT) {
            const float* src = (k0 < DIM) ? (ent_re + (size_t)n * DIM + k0)
                                          : (ent_im + (size_t)n * DIM + (k0 - DIM));
            float4 v0 = ((const float4*)src)[0];
            float4 v1 = ((const float4*)src)[1];
            w.x = pack2_bf16_trunc(v0.x, v0.y);
            w.y = pack2_bf16_trunc(v0.z, v0.w);
            w.z = pack2_bf16_trunc(v1.x, v1.y);
            w.w = pack2_bf16_trunc(v1.z, v1.w);
        } else {
            w = (u32x4){0u, 0u, 0u, 0u};
        }
        *(u32x4*)(Eb + (size_t)n * K2 + k0) = w;
    }
}

// Kernel 2 (fast path): C[1024, 100000] = A[1024,2048](bf16) x Eb^T (bf16).
// m97 structure: both operands staged via global_load_lds width=16; BK=32;
// 2 barriers per K-step; XCD-aware block swizzle (grid 6256 = 8 x 782).
__global__ __launch_bounds__(256) void gemm_bf16(
    const unsigned short* __restrict__ A,   // [1024][2048] bf16
    const unsigned short* __restrict__ Eb,  // [100096][2048] bf16, zero-padded
    float* __restrict__ C)
{
    __shared__ unsigned short As[BM * BK];  // 8 KB, row-major [128][32]
    __shared__ unsigned short Bs[BN * BK];  // 8 KB, row-major [128][32] (= E tile, [n][k])

    // XCD swizzle: hardware round-robins blockIdx over 8 XCDs; give each XCD
    // a contiguous logical chunk so the 8 M-blocks sharing a B strip hit one L2.
    const int bid     = blockIdx.x;
    const int logical = (bid & 7) * (GRID / 8) + (bid >> 3);
    const int mt = logical & (MTILES - 1);  // m fastest: 8 consecutive logicals share entity strip
    const int nt = logical >> 3;
    const int m0 = mt * BM;
    const int n0 = nt * BN;

    const int t    = threadIdx.x;
    const int lane = t & 63;
    const int wave = t >> 6;
    const int wm   = (wave & 1) * 64;
    const int wn   = (wave >> 1) * 64;
    const int fm   = lane & 15;             // frag m (A) / n (B) / col (C)
    const int quad = lane >> 4;             // k-chunk = quad*8 ; C row-quad

    // A staging: 128 rows x 32 bf16 = 8 KB = 2 x (256 lanes x 16B)
    const unsigned short* a_src0 = A + (size_t)(m0 + (t >> 2)) * K2 + (t & 3) * 8;
    const unsigned short* a_src1 = a_src0 + (size_t)64 * K2;
    void* a_dst0 = (char*)As + t * 16;
    void* a_dst1 = (char*)As + 4096 + t * 16;

    // B staging: same shape, rows are (padded) entity rows — no bounds check
    const unsigned short* b_src0 = Eb + (size_t)(n0 + (t >> 2)) * K2 + (t & 3) * 8;
    const unsigned short* b_src1 = b_src0 + (size_t)64 * K2;
    void* b_dst0 = (char*)Bs + t * 16;
    void* b_dst1 = (char*)Bs + 4096 + t * 16;

    f32x4 acc[4][4];
    #pragma unroll
    for (int i = 0; i < 4; ++i)
        #pragma unroll
        for (int j = 0; j < 4; ++j)
            acc[i][j] = (f32x4){0.f, 0.f, 0.f, 0.f};

    for (int kt = 0; kt < K2 / BK; ++kt) {
        const int k0 = kt * BK;

        // async global -> LDS (drained by the compiler's vmcnt(0) at the barrier)
        gld_lds16(a_src0 + k0, a_dst0);
        gld_lds16(a_src1 + k0, a_dst1);
        gld_lds16(b_src0 + k0, b_dst0);
        gld_lds16(b_src1 + k0, b_dst1);

        __syncthreads();

        bf16x8 a_frag[4], b_frag[4];
        #pragma unroll
        for (int i = 0; i < 4; ++i)
            a_frag[i] = *(const bf16x8*)(As + (wm + i * 16 + fm) * BK + quad * 8);
        #pragma unroll
        for (int j = 0; j < 4; ++j)
            b_frag[j] = *(const bf16x8*)(Bs + (wn + j * 16 + fm) * BK + quad * 8);

        #pragma unroll
        for (int i = 0; i < 4; ++i)
            #pragma unroll
            for (int j = 0; j < 4; ++j)
                acc[i][j] = __builtin_amdgcn_mfma_f32_16x16x32_bf16(
                    a_frag[i], b_frag[j], acc[i][j], 0, 0, 0);

        __syncthreads();
    }

    // Epilogue: C/D layout col = lane&15, row = quad*4 + reg  [m89/m91 verified]
    #pragma unroll
    for (int i = 0; i < 4; ++i) {
        #pragma unroll
        for (int j = 0; j < 4; ++j) {
            const int col = n0 + wn + j * 16 + fm;
            if (col < N_ENT) {
                #pragma unroll
                for (int rg = 0; rg < 4; ++rg) {
                    const int row = m0 + wm + i * 16 + quad * 4 + rg;
                    C[(size_t)row * N_ENT + col] = acc[i][j][rg];
                }
            }
        }
    }
}

// Fallback (workspace too small for Eb): previous harness-verified kernel —
// fp32 B gathered + converted in-loop.
__global__ __launch_bounds__(256) void gemm_rotate(
    const unsigned short* __restrict__ A,   // [1024][2048] bf16
    const float* __restrict__ ent_re,
    const float* __restrict__ ent_im,
    float* __restrict__ C)
{
    __shared__ unsigned short As[BM * BK];
    __shared__ unsigned short Bs[BN * BK];

    const int bid = blockIdx.x;
    const int mt  = bid & (MTILES - 1);
    const int nt  = bid >> 3;
    const int m0  = mt * BM;
    const int n0  = nt * BN;

    const int t    = threadIdx.x;
    const int lane = t & 63;
    const int wave = t >> 6;
    const int wm   = (wave & 1) * 64;
    const int wn   = (wave >> 1) * 64;
    const int fm   = lane & 15;
    const int quad = lane >> 4;

    const unsigned short* a_src0 = A + (size_t)(m0 + (t >> 2)) * K2 + (t & 3) * 8;
    const unsigned short* a_src1 = A + (size_t)(m0 + 64 + (t >> 2)) * K2 + (t & 3) * 8;
    void* a_dst0 = (char*)As + t * 16;
    void* a_dst1 = (char*)As + 4096 + t * 16;

    const int b_row   = t >> 1;
    const int b_col   = (t & 1) * 16;
    const int n_idx   = n0 + b_row;
    const bool b_valid = (n_idx < N_ENT);
    const size_t b_off = (size_t)(b_valid ? n_idx : 0) * DIM + b_col;
    unsigned short* b_dst = Bs + b_row * BK + b_col;

    f32x4 acc[4][4];
    #pragma unroll
    for (int i = 0; i < 4; ++i)
        #pragma unroll
        for (int j = 0; j < 4; ++j)
            acc[i][j] = (f32x4){0.f, 0.f, 0.f, 0.f};

    for (int kt = 0; kt < K2 / BK; ++kt) {
        const int k0 = kt * BK;
        const float* E = (k0 < DIM) ? ent_re : ent_im;
        const int ke = k0 & (DIM - 1);

        gld_lds16(a_src0 + k0, a_dst0);
        gld_lds16(a_src1 + k0, a_dst1);

        float4 v0, v1, v2, v3;
        if (b_valid) {
            const float4* src = (const float4*)(E + b_off + ke);
            v0 = src[0]; v1 = src[1]; v2 = src[2]; v3 = src[3];
        } else {
            v0 = v1 = v2 = v3 = (float4){0.f, 0.f, 0.f, 0.f};
        }
        u32x4 w0, w1;
        w0.x = pack2_bf16_trunc(v0.x, v0.y); w0.y = pack2_bf16_trunc(v0.z, v0.w);
        w0.z = pack2_bf16_trunc(v1.x, v1.y); w0.w = pack2_bf16_trunc(v1.z, v1.w);
        w1.x = pack2_bf16_trunc(v2.x, v2.y); w1.y = pack2_bf16_trunc(v2.z, v2.w);
        w1.z = pack2_bf16_trunc(v3.x, v3.y); w1.w = pack2_bf16_trunc(v3.z, v3.w);
        *(u32x4*)(b_dst)     = w0;
        *(u32x4*)(b_dst + 8) = w1;

        __syncthreads();

        bf16x8 a_frag[4], b_frag[4];
        #pragma unroll
        for (int i = 0; i < 4; ++i)
            a_frag[i] = *(const bf16x8*)(As + (wm + i * 16 + fm) * BK + quad * 8);
        #pragma unroll
        for (int j = 0; j < 4; ++j)
            b_frag[j] = *(const bf16x8*)(Bs + (wn + j * 16 + fm) * BK + quad * 8);

        #pragma unroll
        for (int i = 0; i < 4; ++i)
            #pragma unroll
            for (int j = 0; j < 4; ++j)
                acc[i][j] = __builtin_amdgcn_mfma_f32_16x16x32_bf16(
                    a_frag[i], b_frag[j], acc[i][j], 0, 0, 0);

        __syncthreads();
    }

    #pragma unroll
    for (int i = 0; i < 4; ++i) {
        #pragma unroll
        for (int j = 0; j < 4; ++j) {
            const int col = n0 + wn + j * 16 + fm;
            if (col < N_ENT) {
                #pragma unroll
                for (int rg = 0; rg < 4; ++rg) {
                    const int row = m0 + wm + i * 16 + quad * 4 + rg;
                    C[(size_t)row * N_ENT + col] = acc[i][j][rg];
                }
            }
        }
    }
}

extern "C" void kernel_launch(void* const* d_in, const int* in_sizes, int n_in,
                              void* d_out, int out_size, void* d_ws, size_t ws_size,
                              hipStream_t stream) {
    const int*   e1        = (const int*)d_in[0];
    const int*   r         = (const int*)d_in[1];
    const float* ent_re    = (const float*)d_in[2];
    const float* ent_im    = (const float*)d_in[3];
    const float* rel_phase = (const float*)d_in[4];
    float* out = (float*)d_out;

    unsigned short* A = (unsigned short*)d_ws;                 // 4 MB
    const size_t A_BYTES  = (size_t)BATCH * K2 * sizeof(unsigned short);
    const size_t EB_BYTES = (size_t)NPAD * K2 * sizeof(unsigned short);  // ~410 MB

    rotate_build_A<<<BATCH, 256, 0, stream>>>(e1, r, ent_re, ent_im, rel_phase, A);

    if (ws_size >= A_BYTES + EB_BYTES) {
        unsigned short* Eb = (unsigned short*)((char*)d_ws + A_BYTES);
        convert_E<<<2048, 256, 0, stream>>>(ent_re, ent_im, Eb);
        gemm_bf16<<<GRID, 256, 0, stream>>>(A, Eb, out);
    } else {
        gemm_rotate<<<GRID, 256, 0, stream>>>(A, ent_re, ent_im, out);
    }
}